// Round 5
// baseline (728.225 us; speedup 1.0000x reference)
//
#include <hip/hip_runtime.h>
#include <math.h>

typedef __bf16 bf16;
typedef __attribute__((ext_vector_type(8))) __bf16 bf16x8;
typedef __attribute__((ext_vector_type(4))) float floatx4;

#define DIM 512
#define DFF 2048
#define SEQ 4096
#define ROWS 32768            // 8 * 4096

#define GLOBAL_AS(p) ((const __attribute__((address_space(1))) void*)(p))
#define LDS_AS(p)    ((__attribute__((address_space(3))) void*)(p))

// ---------------- weight prep: fp32 [K][N] -> bf16 [N][K] (transposed) ----------------
__global__ __launch_bounds__(256) void prep_w_kernel(const float* __restrict__ W,
                                                     bf16* __restrict__ Wt, int K, int N)
{
    int idx = blockIdx.x * 256 + threadIdx.x;
    if (idx >= K * N) return;
    int k = idx % K;
    int n = idx / K;
    Wt[idx] = (bf16)W[(size_t)k * N + n];
}

__global__ __launch_bounds__(256) void pack_bias_kernel(const float* __restrict__ bq,
                                                        const float* __restrict__ bk,
                                                        const float* __restrict__ bv,
                                                        float* __restrict__ out)
{
    int i = blockIdx.x * 256 + threadIdx.x;
    if (i >= 1536) return;
    out[i] = (i < 512) ? bq[i] : (i < 1024 ? bk[i - 512] : bv[i - 1024]);
}

// ---------------- wave reduction ----------------
__device__ inline float wave_red(float v)
{
#pragma unroll
    for (int off = 32; off; off >>= 1) v += __shfl_xor(v, off, 64);
    return v;
}

// ---------------- fused series-decomposition + LayerNorm1 ----------------
__global__ __launch_bounds__(256) void decomp_ln_kernel(const float* __restrict__ x,
                                                        const float* __restrict__ g,
                                                        const float* __restrict__ be,
                                                        float* __restrict__ S,
                                                        bf16* __restrict__ XN)
{
    int wave = threadIdx.x >> 6, lane = threadIdx.x & 63;
    int r = blockIdx.x * 4 + wave;
    int n = r & (SEQ - 1);
    const float4* xr = (const float4*)(x + (size_t)r * DIM);
    float4 z = make_float4(0.f, 0.f, 0.f, 0.f);
    float s[8];
#pragma unroll
    for (int i = 0; i < 2; ++i) {
        int c4 = lane * 2 + i;
        float4 v0 = xr[c4];
        float4 vm = (n > 0)       ? xr[c4 - DIM / 4] : z;
        float4 vp = (n < SEQ - 1) ? xr[c4 + DIM / 4] : z;
        s[i * 4 + 0] = v0.x - (vm.x + v0.x + vp.x) * (1.f / 3.f);
        s[i * 4 + 1] = v0.y - (vm.y + v0.y + vp.y) * (1.f / 3.f);
        s[i * 4 + 2] = v0.z - (vm.z + v0.z + vp.z) * (1.f / 3.f);
        s[i * 4 + 3] = v0.w - (vm.w + v0.w + vp.w) * (1.f / 3.f);
    }
    float4* Sr = (float4*)(S + (size_t)r * DIM);
    Sr[lane * 2]     = make_float4(s[0], s[1], s[2], s[3]);
    Sr[lane * 2 + 1] = make_float4(s[4], s[5], s[6], s[7]);

    float sum = 0.f;
#pragma unroll
    for (int j = 0; j < 8; ++j) sum += s[j];
    sum = wave_red(sum);
    float mean = sum * (1.f / DIM);
    float vs = 0.f;
#pragma unroll
    for (int j = 0; j < 8; ++j) { float d = s[j] - mean; vs += d * d; }
    vs = wave_red(vs);
    float rstd = rsqrtf(vs * (1.f / DIM) + 1e-5f);

    int c = lane * 8;
    float4 g0 = ((const float4*)(g + c))[0],  g1v = ((const float4*)(g + c))[1];
    float4 b0 = ((const float4*)(be + c))[0], b1v = ((const float4*)(be + c))[1];
    bf16x8 o;
    o[0] = (bf16)((s[0] - mean) * rstd * g0.x + b0.x);
    o[1] = (bf16)((s[1] - mean) * rstd * g0.y + b0.y);
    o[2] = (bf16)((s[2] - mean) * rstd * g0.z + b0.z);
    o[3] = (bf16)((s[3] - mean) * rstd * g0.w + b0.w);
    o[4] = (bf16)((s[4] - mean) * rstd * g1v.x + b1v.x);
    o[5] = (bf16)((s[5] - mean) * rstd * g1v.y + b1v.y);
    o[6] = (bf16)((s[6] - mean) * rstd * g1v.z + b1v.z);
    o[7] = (bf16)((s[7] - mean) * rstd * g1v.w + b1v.w);
    *(bf16x8*)(XN + (size_t)r * DIM + c) = o;
}

// ---------------- LN2 + fold residual: XN = LN(S), S_out = S + trend(x) ----------------
__global__ __launch_bounds__(256) void ln_trend_kernel(const float* __restrict__ x,
                                                       const float* __restrict__ g,
                                                       const float* __restrict__ be,
                                                       float* __restrict__ S,
                                                       bf16* __restrict__ XN)
{
    int wave = threadIdx.x >> 6, lane = threadIdx.x & 63;
    int r = blockIdx.x * 4 + wave;
    int n = r & (SEQ - 1);
    float4* Sr = (float4*)(S + (size_t)r * DIM);
    float4 a0 = Sr[lane * 2], a1 = Sr[lane * 2 + 1];
    float s[8] = {a0.x, a0.y, a0.z, a0.w, a1.x, a1.y, a1.z, a1.w};
    float sum = 0.f;
#pragma unroll
    for (int j = 0; j < 8; ++j) sum += s[j];
    sum = wave_red(sum);
    float mean = sum * (1.f / DIM);
    float vs = 0.f;
#pragma unroll
    for (int j = 0; j < 8; ++j) { float d = s[j] - mean; vs += d * d; }
    vs = wave_red(vs);
    float rstd = rsqrtf(vs * (1.f / DIM) + 1e-5f);
    int c = lane * 8;
    float4 g0 = ((const float4*)(g + c))[0],  g1v = ((const float4*)(g + c))[1];
    float4 b0 = ((const float4*)(be + c))[0], b1v = ((const float4*)(be + c))[1];
    bf16x8 o;
    o[0] = (bf16)((s[0] - mean) * rstd * g0.x + b0.x);
    o[1] = (bf16)((s[1] - mean) * rstd * g0.y + b0.y);
    o[2] = (bf16)((s[2] - mean) * rstd * g0.z + b0.z);
    o[3] = (bf16)((s[3] - mean) * rstd * g0.w + b0.w);
    o[4] = (bf16)((s[4] - mean) * rstd * g1v.x + b1v.x);
    o[5] = (bf16)((s[5] - mean) * rstd * g1v.y + b1v.y);
    o[6] = (bf16)((s[6] - mean) * rstd * g1v.z + b1v.z);
    o[7] = (bf16)((s[7] - mean) * rstd * g1v.w + b1v.w);
    *(bf16x8*)(XN + (size_t)r * DIM + c) = o;

    // S += trend(x)
    const float4* xr = (const float4*)(x + (size_t)r * DIM);
    float4 z = make_float4(0.f, 0.f, 0.f, 0.f);
#pragma unroll
    for (int i = 0; i < 2; ++i) {
        int c4 = lane * 2 + i;
        float4 v0 = xr[c4];
        float4 vm = (n > 0)       ? xr[c4 - DIM / 4] : z;
        float4 vp = (n < SEQ - 1) ? xr[c4 + DIM / 4] : z;
        float4 sv = (i == 0) ? a0 : a1;
        sv.x += (vm.x + v0.x + vp.x) * (1.f / 3.f);
        sv.y += (vm.y + v0.y + vp.y) * (1.f / 3.f);
        sv.z += (vm.z + v0.z + vp.z) * (1.f / 3.f);
        sv.w += (vm.w + v0.w + vp.w) * (1.f / 3.f);
        Sr[c4] = sv;
    }
}

// ---------------- MFMA GEMM with XOR-swizzled LDS (conflict-free fragment reads) ---------
// C = A[M,K](bf16) @ Bt[N,K]^T(bf16) + bias.  Modes: QKV (elu+1 on q,k -> bf16),
// ACC (S += val), FFN1 (gelu -> bf16).
enum { M_QKV = 0, M_ACC = 1, M_FFN1 = 2 };

template <int MODE>
__global__ __launch_bounds__(256) void gemm_bt_kernel(const bf16* __restrict__ A, int lda,
                                                      const bf16* __restrict__ Bt,
                                                      const float* __restrict__ bias,
                                                      float* S, void* Cout, int ldc,
                                                      int N, int K, int rows_per_batch)
{
    __shared__ __align__(16) bf16 lA[128 * 32];
    __shared__ __align__(16) bf16 lB[128 * 32];
    int tid = threadIdx.x;
    int m0 = blockIdx.y * 128;
    int n0 = blockIdx.x * 128;
    const bf16* Abase = A + (size_t)m0 * lda;
    const bf16* Bbase = Bt + (size_t)n0 * K;
    if (rows_per_batch) Bbase += (size_t)(m0 / rows_per_batch) * (size_t)N * K;

    int lane = tid & 63;
    int wave = tid >> 6;
    int wm = (wave >> 1) * 64;
    int wn = (wave & 1) * 64;
    int lm = lane & 15;
    int quad = lane >> 4;
    int i0w = tid & 192;
    int swz = (lm >> 1) & 3;           // fragment-read chunk swizzle

    floatx4 acc[4][4];
#pragma unroll
    for (int i = 0; i < 4; ++i)
#pragma unroll
        for (int j = 0; j < 4; ++j) acc[i][j] = (floatx4){0.f, 0.f, 0.f, 0.f};

    for (int k0 = 0; k0 < K; k0 += 32) {
        __syncthreads();
#pragma unroll
        for (int it = 0; it < 2; ++it) {
            int ib = it * 256 + i0w;
            int i  = ib + lane;
            int row = i >> 2;
            // store-side swizzle: slot (row, i&3) holds global chunk (i&3)^((row>>1)&3)
            int col = ((i & 3) ^ ((row >> 1) & 3)) * 8;
            __builtin_amdgcn_global_load_lds(GLOBAL_AS(Abase + (size_t)row * lda + k0 + col),
                                             LDS_AS(&lA[ib * 8]), 16, 0, 0);
            __builtin_amdgcn_global_load_lds(GLOBAL_AS(Bbase + (size_t)row * K + k0 + col),
                                             LDS_AS(&lB[ib * 8]), 16, 0, 0);
        }
        __syncthreads();

        bf16x8 af[4], bfv[4];
#pragma unroll
        for (int i = 0; i < 4; ++i)
            af[i] = *(const bf16x8*)&lA[(wm + i * 16 + lm) * 32 + (quad ^ swz) * 8];
#pragma unroll
        for (int j = 0; j < 4; ++j)
            bfv[j] = *(const bf16x8*)&lB[(wn + j * 16 + lm) * 32 + (quad ^ swz) * 8];
#pragma unroll
        for (int i = 0; i < 4; ++i)
#pragma unroll
            for (int j = 0; j < 4; ++j)
                acc[i][j] = __builtin_amdgcn_mfma_f32_16x16x32_bf16(af[i], bfv[j], acc[i][j], 0, 0, 0);
    }

    // epilogue: C/D layout col = lane&15, row = quad*4 + e (m89-verified)
#pragma unroll
    for (int i = 0; i < 4; ++i) {
        int gm_base = m0 + wm + i * 16 + quad * 4;
#pragma unroll
        for (int j = 0; j < 4; ++j) {
            int gn = n0 + wn + j * 16 + lm;
            float bia = bias[gn];
#pragma unroll
            for (int e = 0; e < 4; ++e) {
                int gm = gm_base + e;
                float val = acc[i][j][e] + bia;
                if constexpr (MODE == M_QKV) {
                    if (gn < 1024) val = (val > 0.f) ? val + 1.f : __expf(val);  // elu+1 on q,k
                    ((bf16*)Cout)[(size_t)gm * ldc + gn] = (bf16)val;
                } else if constexpr (MODE == M_ACC) {
                    S[(size_t)gm * DIM + gn] += val;
                } else {  // M_FFN1
                    val = 0.5f * val * (1.f + erff(val * 0.70710678118654752f));  // exact gelu
                    ((bf16*)Cout)[(size_t)gm * ldc + gn] = (bf16)val;
                }
            }
        }
    }
}

// ---------------- kv einsum via MFMA: KV[kc][b*8+h][d][f] = sum_n k[n][d]*v[n][f] ----------
__global__ __launch_bounds__(256) void kv_mfma_kernel(const bf16* __restrict__ QKV,
                                                      float* __restrict__ KV)
{
    int kc = blockIdx.x, h = blockIdx.y, b = blockIdx.z;
    __shared__ __align__(16) bf16 lbuf[2 * 128 * 64];
    bf16* lk = lbuf;
    bf16* lv = lbuf + 128 * 64;
    int tid = threadIdx.x;
    int lane = tid & 63, wave = tid >> 6;
    int lm = lane & 15, quad = lane >> 4;

    floatx4 acc[4][4];
#pragma unroll
    for (int i = 0; i < 4; ++i)
#pragma unroll
        for (int j = 0; j < 4; ++j) acc[i][j] = (floatx4){0.f, 0.f, 0.f, 0.f};

    const bf16* kb = QKV + (size_t)b * SEQ * 1536 + 512 + (size_t)h * 64;
    const bf16* vb = kb + 512;
    int drow = lane >> 3;
    int d0 = (lane & 7) * 8;

    for (int it = 0; it < 8; ++it) {
        int n0 = kc * 1024 + it * 128;
        __syncthreads();
#pragma unroll
        for (int q = 0; q < 4; ++q) {
            int nbase = wave * 32 + q * 8;
            int ldsoff = wave * 2048 + q * 512;
            __builtin_amdgcn_global_load_lds(GLOBAL_AS(kb + (size_t)(n0 + nbase + drow) * 1536 + d0),
                                             LDS_AS(&lk[ldsoff]), 16, 0, 0);
            __builtin_amdgcn_global_load_lds(GLOBAL_AS(vb + (size_t)(n0 + nbase + drow) * 1536 + d0),
                                             LDS_AS(&lv[ldsoff]), 16, 0, 0);
        }
        __syncthreads();

        int nw = wave * 32 + quad * 8;
        bf16x8 af[4], bfv[4];
#pragma unroll
        for (int i = 0; i < 4; ++i) {
            int dd = i * 16 + lm;
#pragma unroll
            for (int j = 0; j < 8; ++j) af[i][j] = lk[(nw + j) * 64 + dd];
#pragma unroll
            for (int j = 0; j < 8; ++j) bfv[i][j] = lv[(nw + j) * 64 + dd];
        }
#pragma unroll
        for (int i = 0; i < 4; ++i)
#pragma unroll
            for (int j = 0; j < 4; ++j)
                acc[i][j] = __builtin_amdgcn_mfma_f32_16x16x32_bf16(af[i], bfv[j], acc[i][j], 0, 0, 0);
    }

    __syncthreads();
    float* red = (float*)lbuf;
    if (wave < 2) {
#pragma unroll
        for (int i = 0; i < 4; ++i)
#pragma unroll
            for (int j = 0; j < 4; ++j)
#pragma unroll
                for (int e = 0; e < 4; ++e)
                    red[wave * 4096 + (i * 16 + quad * 4 + e) * 64 + j * 16 + lm] = acc[i][j][e];
    }
    __syncthreads();
    if (wave >= 2) {
#pragma unroll
        for (int i = 0; i < 4; ++i)
#pragma unroll
            for (int j = 0; j < 4; ++j)
#pragma unroll
                for (int e = 0; e < 4; ++e)
                    red[(wave - 2) * 4096 + (i * 16 + quad * 4 + e) * 64 + j * 16 + lm] += acc[i][j][e];
    }
    __syncthreads();
    float* dst = KV + ((size_t)kc * 64 + b * 8 + h) * 4096;
#pragma unroll
    for (int p = 0; p < 4; ++p) {
        int e4 = (tid + p * 256) * 4;
        float4 a = *(const float4*)&red[e4];
        float4 c4 = *(const float4*)&red[4096 + e4];
        a.x += c4.x; a.y += c4.y; a.z += c4.z; a.w += c4.w;
        *(float4*)&dst[e4] = a;
    }
}

// ---------------- fold Wo (reduce 4 kc-partials): KVWT[b][j][h*64+d] ----------------
__global__ __launch_bounds__(256) void kvw_kernel(const float* __restrict__ KV,
                                                  const float* __restrict__ Wo,
                                                  bf16* __restrict__ KVWT)
{
    int jc = blockIdx.x & 7, bh = blockIdx.x >> 3;
    int h = bh & 7, b = bh >> 3;
    __shared__ float skvT[64 * 68];
    int tid = threadIdx.x;
    const float* src = KV + (size_t)bh * 4096;
#pragma unroll
    for (int p = 0; p < 16; ++p) {
        int e = tid + p * 256;
        float s = src[e] + src[e + 262144] + src[e + 524288] + src[e + 786432];
        skvT[(e & 63) * 68 + (e >> 6)] = s;
    }
    __syncthreads();

    int j = tid & 63, dq = tid >> 6;
    int j0 = jc * 64;
    floatx4 acc4[4];
#pragma unroll
    for (int c = 0; c < 4; ++c) acc4[c] = (floatx4){0.f, 0.f, 0.f, 0.f};
    const float* wop = Wo + (size_t)h * 64 * 512 + j0 + j;
#pragma unroll 8
    for (int f = 0; f < 64; ++f) {
        float w = wop[(size_t)f * 512];
        const float* sp = &skvT[f * 68 + dq * 16];
#pragma unroll
        for (int c = 0; c < 4; ++c) {
            floatx4 s = *(const floatx4*)(sp + c * 4);
            acc4[c] += s * w;
        }
    }
    bf16* dst = KVWT + (size_t)b * 262144 + (size_t)(j0 + j) * 512 + h * 64 + dq * 16;
    bf16x8 o0, o1;
#pragma unroll
    for (int t = 0; t < 8; ++t) { o0[t] = (bf16)acc4[t >> 2][t & 3]; o1[t] = (bf16)acc4[2 + (t >> 2)][t & 3]; }
    *(bf16x8*)dst = o0;
    *(bf16x8*)(dst + 8) = o1;
}

// ---------------- launch ----------------
extern "C" void kernel_launch(void* const* d_in, const int* in_sizes, int n_in,
                              void* d_out, int out_size, void* d_ws, size_t ws_size,
                              hipStream_t stream)
{
    const float* x   = (const float*)d_in[0];
    const float* Wq  = (const float*)d_in[1];
    const float* bq  = (const float*)d_in[2];
    const float* Wk  = (const float*)d_in[3];
    const float* bk  = (const float*)d_in[4];
    const float* Wv  = (const float*)d_in[5];
    const float* bv  = (const float*)d_in[6];
    const float* Wo  = (const float*)d_in[7];
    const float* bo  = (const float*)d_in[8];
    const float* g1  = (const float*)d_in[9];
    const float* b1  = (const float*)d_in[10];
    const float* g2  = (const float*)d_in[11];
    const float* b2  = (const float*)d_in[12];
    const float* Wf1 = (const float*)d_in[13];
    const float* bf1 = (const float*)d_in[14];
    const float* Wf2 = (const float*)d_in[15];
    const float* bf2 = (const float*)d_in[16];
    float* out = (float*)d_out;      // holds seasonal residual S, then final output
    (void)in_sizes; (void)n_in; (void)out_size;

    char* ws = (char*)d_ws;
    size_t off = 0;
    auto alloc = [&](size_t bytes) -> char* {
        char* p = ws + off;
        off += (bytes + 255) & ~(size_t)255;
        return p;
    };
    bf16*  WqkvT = (bf16*)alloc((size_t)1536 * 512 * 2);
    float* bias3 = (float*)alloc(1536 * 4);
    bf16*  Wf1T  = (bf16*)alloc((size_t)2048 * 512 * 2);
    bf16*  Wf2T  = (bf16*)alloc((size_t)512 * 2048 * 2);
    bf16*  XN    = (bf16*)alloc((size_t)ROWS * DIM * 2);
    float* KV    = (float*)alloc((size_t)4 * 64 * 4096 * 4);
    bf16*  KVWT  = (bf16*)alloc((size_t)8 * 512 * 512 * 2);
    bf16*  QKV   = (bf16*)alloc((size_t)ROWS * 1536 * 2);
    size_t base_need = off;
    size_t h1_full = (size_t)ROWS * DFF * 2;             // 134.2 MB
    bool big = (ws_size >= base_need + h1_full);
    bf16* H1 = big ? (bf16*)alloc(h1_full) : QKV;        // alias QKV if ws is small
    int n_chunks   = big ? 1 : 2;
    int chunk_rows = big ? ROWS : ROWS / 2;

    prep_w_kernel<<<1024, 256, 0, stream>>>(Wq, WqkvT,              512, 512);
    prep_w_kernel<<<1024, 256, 0, stream>>>(Wk, WqkvT + 512 * 512,  512, 512);
    prep_w_kernel<<<1024, 256, 0, stream>>>(Wv, WqkvT + 1024 * 512, 512, 512);
    prep_w_kernel<<<4096, 256, 0, stream>>>(Wf1, Wf1T, 512, 2048);
    prep_w_kernel<<<4096, 256, 0, stream>>>(Wf2, Wf2T, 2048, 512);
    pack_bias_kernel<<<6, 256, 0, stream>>>(bq, bk, bv, bias3);

    decomp_ln_kernel<<<8192, 256, 0, stream>>>(x, g1, b1, out, XN);

    gemm_bt_kernel<M_QKV><<<dim3(12, 256), 256, 0, stream>>>(
        XN, 512, WqkvT, bias3, nullptr, QKV, 1536, 1536, 512, 0);

    kv_mfma_kernel<<<dim3(4, 8, 8), 256, 0, stream>>>(QKV, KV);

    kvw_kernel<<<512, 256, 0, stream>>>(KV, Wo, KVWT);

    gemm_bt_kernel<M_ACC><<<dim3(4, 256), 256, 0, stream>>>(
        QKV, 1536, KVWT, bo, out, nullptr, 0, 512, 512, 4096);

    // LN2 + fold trend residual into S (out = S + trend; XN = LN(S))
    ln_trend_kernel<<<8192, 256, 0, stream>>>(x, g2, b2, out, XN);

    for (int c = 0; c < n_chunks; ++c) {
        gemm_bt_kernel<M_FFN1><<<dim3(16, chunk_rows / 128), 256, 0, stream>>>(
            XN + (size_t)c * chunk_rows * 512, 512, Wf1T, bf1, nullptr,
            H1, 2048, 2048, 512, 0);
        gemm_bt_kernel<M_ACC><<<dim3(4, chunk_rows / 128), 256, 0, stream>>>(
            H1, 2048, Wf2T, bf2, out + (size_t)c * chunk_rows * 512, nullptr,
            0, 512, 2048, 0);
    }
}